// Round 13
// baseline (172.440 us; speedup 1.0000x reference)
//
#include <hip/hip_runtime.h>

#define N_NODES 100000
#define N_EDGES 1600000
#define HIDDEN  128

// bucket partition geometry
#define NPB_SHIFT 9
#define NPB       512                                   // nodes per bucket
#define NB        ((N_NODES + NPB - 1) / NPB)           // 196 buckets
#define PART_T    512                                   // threads per part block
#define PART_EPT  12                                    // edges per thread
#define PART_EPB  (PART_T * PART_EPT)                   // 6144 edges per block
#define PART_B    ((N_EDGES + PART_EPB - 1) / PART_EPB) // 261 blocks (~1/CU)
#define HIST_EPT  16
#define HIST_EPB  (256 * HIST_EPT)                      // 4096
#define HIST_B    ((N_EDGES + HIST_EPB - 1) / HIST_EPB) // 391
#define GATES_B   ((N_NODES * 32 + 255) / 256)          // 12500 blocks
#define FINE_PE   20                                    // regs/thread in fine

// legacy-scan geometry (fallback path only)
#define SCAN_C 16
#define SCAN_T ((N_NODES + SCAN_C - 1) / SCAN_C)
#define SCAN_THREADS 6400
#define SCAN_B (SCAN_THREADS / 256)

// float -> bf16 round-to-nearest-even
__device__ __forceinline__ ushort f2bf(float f) {
    unsigned int u = __float_as_uint(f);
    u = (u + 0x7FFFu + ((u >> 16) & 1u)) >> 16;
    return (ushort)u;
}

// ---------------------------------------------------------------------------
// Tiny zero kernel: bcnt[NB] = 0
// ---------------------------------------------------------------------------
__global__ void fagcn_zero(int* __restrict__ bcnt) {
    const int t = (int)threadIdx.x;
    if (t < NB) bcnt[t] = 0;
}

// ---------------------------------------------------------------------------
// Fused kernel: blocks [0, GATES_B) do per-node gates (+bf16 x copy);
// blocks [GATES_B, GATES_B+HIST_B) do the bucket histogram of in_idx.
// ---------------------------------------------------------------------------
__global__ void fagcn_gates_hist(const float* __restrict__ x,
                                 const float* __restrict__ w1,
                                 const float* __restrict__ w2,
                                 const int*   __restrict__ in_idx,
                                 float* __restrict__ g1,
                                 float* __restrict__ g2,
                                 int*   __restrict__ bcnt,
                                 ushort* __restrict__ xh,
                                 int write_xh,
                                 int with_hist) {
    __shared__ int cnt[NB];
    if ((int)blockIdx.x < GATES_B) {
        // ---- gates role ----
        const int tid  = blockIdx.x * 256 + (int)threadIdx.x;
        const int node = tid >> 5;                 // 32 lanes per node
        const int hl   = (int)(threadIdx.x & 31);
        if (node >= N_NODES) return;

        const float4 xv  = *reinterpret_cast<const float4*>(x  + (size_t)node * HIDDEN + hl * 4);
        const float4 w1v = *reinterpret_cast<const float4*>(w1 + hl * 4);
        const float4 w2v = *reinterpret_cast<const float4*>(w2 + hl * 4);

        if (write_xh) {
            ushort4 h;
            h.x = f2bf(xv.x); h.y = f2bf(xv.y); h.z = f2bf(xv.z); h.w = f2bf(xv.w);
            *reinterpret_cast<ushort4*>(xh + (size_t)node * HIDDEN + hl * 4) = h;
        }

        float s1 = xv.x * w1v.x + xv.y * w1v.y + xv.z * w1v.z + xv.w * w1v.w;
        float s2 = xv.x * w2v.x + xv.y * w2v.y + xv.z * w2v.z + xv.w * w2v.w;

        #pragma unroll
        for (int off = 16; off > 0; off >>= 1) {
            s1 += __shfl_down(s1, off, 32);
            s2 += __shfl_down(s2, off, 32);
        }
        if (hl == 0) { g1[node] = s1; g2[node] = s2; }
    } else if (with_hist) {
        // ---- bucket histogram role ----
        const int tid  = (int)threadIdx.x;
        const int base = ((int)blockIdx.x - GATES_B) * HIST_EPB + tid * HIST_EPT;
        for (int j = tid; j < NB; j += 256) cnt[j] = 0;
        __syncthreads();
        if (base < N_EDGES) {                      // N_EDGES % HIST_EPT == 0
            #pragma unroll
            for (int i = 0; i < 4; ++i) {
                const int4 v = *reinterpret_cast<const int4*>(in_idx + base + i * 4);
                atomicAdd(&cnt[v.x >> NPB_SHIFT], 1);
                atomicAdd(&cnt[v.y >> NPB_SHIFT], 1);
                atomicAdd(&cnt[v.z >> NPB_SHIFT], 1);
                atomicAdd(&cnt[v.w >> NPB_SHIFT], 1);
            }
        }
        __syncthreads();
        for (int j = tid; j < NB; j += 256)
            if (cnt[j]) atomicAdd(&bcnt[j], cnt[j]);
    }
}

// ---------------------------------------------------------------------------
// Bucket scan: exclusive scan of NB bucket counts -> sbase (1 tiny block);
// sbase[NB] = N_EDGES; zeroes bcur.
// ---------------------------------------------------------------------------
__global__ void fagcn_scanb(const int* __restrict__ bcnt,
                            int* __restrict__ sbase,
                            int* __restrict__ bcur) {
    __shared__ int l[256];
    const int t = (int)threadIdx.x;
    const int c = (t < NB) ? bcnt[t] : 0;
    l[t] = c;
    __syncthreads();
    for (int off = 1; off < 256; off <<= 1) {
        int v = (t >= off) ? l[t - off] : 0;
        __syncthreads();
        l[t] += v;
        __syncthreads();
    }
    if (t < NB) { sbase[t] = l[t] - c; bcur[t] = 0; }
    if (t == NB - 1) sbase[NB] = l[t];             // == N_EDGES
}

// ---------------------------------------------------------------------------
// Partition pass: 261 blocks x 512 threads x EPT 12 -> ~1 block/CU (full
// occupancy for latency hiding) with only 261*196=51K chunk boundaries.
// ---------------------------------------------------------------------------
__global__ void fagcn_part(const float* __restrict__ adj,
                           const int*   __restrict__ in_idx,
                           const int*   __restrict__ out_idx,
                           const float* __restrict__ g1,
                           const float* __restrict__ g2,
                           const int*   __restrict__ sbase,
                           int*         __restrict__ bcur,
                           int2*        __restrict__ stage) {
    __shared__ int cnt[NB], lbase[NB], lcur[NB];
    const int tid  = (int)threadIdx.x;                 // 0..511
    const int base = blockIdx.x * PART_EPB + tid * PART_EPT;

    for (int j = tid; j < NB; j += PART_T) { cnt[j] = 0; lcur[j] = 0; }
    __syncthreads();

    int  s[PART_EPT];
    bool ga[PART_EPT / 4];
    #pragma unroll
    for (int i = 0; i < PART_EPT / 4; ++i) {
        ga[i] = (base + i * 4 < N_EDGES);              // N_EDGES % 4 == 0
        if (ga[i]) {
            const int4 v = *reinterpret_cast<const int4*>(in_idx + base + i * 4);
            s[4 * i + 0] = v.x; s[4 * i + 1] = v.y;
            s[4 * i + 2] = v.z; s[4 * i + 3] = v.w;
            atomicAdd(&cnt[v.x >> NPB_SHIFT], 1);
            atomicAdd(&cnt[v.y >> NPB_SHIFT], 1);
            atomicAdd(&cnt[v.z >> NPB_SHIFT], 1);
            atomicAdd(&cnt[v.w >> NPB_SHIFT], 1);
        }
    }
    __syncthreads();
    for (int j = tid; j < NB; j += PART_T)
        if (cnt[j] > 0) lbase[j] = sbase[j] + atomicAdd(&bcur[j], cnt[j]);
    __syncthreads();
    #pragma unroll
    for (int i = 0; i < PART_EPT / 4; ++i) {
        if (!ga[i]) continue;
        const int4   d4 = *reinterpret_cast<const int4*>(out_idx + base + i * 4);
        const float4 a4 = *reinterpret_cast<const float4*>(adj + base + i * 4);
        const int   dd[4] = {d4.x, d4.y, d4.z, d4.w};
        const float aa[4] = {a4.x, a4.y, a4.z, a4.w};
        #pragma unroll
        for (int k = 0; k < 4; ++k) {
            const int src = s[4 * i + k];
            const int dst = dd[k];
            const float m = tanhf(g1[src] + g2[dst]) * aa[k];
            const int b   = src >> NPB_SHIFT;
            const int pos = lbase[b] + atomicAdd(&lcur[b], 1);
            stage[pos] = make_int2(((src & (NPB - 1)) << 17) | dst,
                                   __float_as_int(m));
        }
    }
}

// ---------------------------------------------------------------------------
// Fine binning: one block per bucket, single pass (payload in registers).
// ---------------------------------------------------------------------------
__global__ void fagcn_fine(const int2* __restrict__ stage,
                           const int*  __restrict__ sbase,
                           int*        __restrict__ offsets,
                           int2*       __restrict__ sedge) {
    __shared__ int cnt[NPB];
    __shared__ int cur[NPB];
    const int b = (int)blockIdx.x;
    const int t = (int)threadIdx.x;            // 0..511

    const int ebeg = sbase[b];
    const int eend = sbase[b + 1];

    cnt[t] = 0;
    __syncthreads();

    // load payload into registers + LDS per-node count
    int2 pay[FINE_PE];
    #pragma unroll
    for (int i = 0; i < FINE_PE; ++i) {
        const int e = ebeg + t + i * NPB;
        if (e < eend) {
            pay[i] = stage[e];
            atomicAdd(&cnt[pay[i].x >> 17], 1);
        }
    }
    __syncthreads();

    // exclusive scan over NPB node counts
    const int c = cnt[t];
    for (int off = 1; off < NPB; off <<= 1) {
        int v = (t >= off) ? cnt[t - off] : 0;
        __syncthreads();
        cnt[t] += v;
        __syncthreads();
    }
    const int excl = cnt[t] - c;
    cur[t] = ebeg + excl;
    const int node = (b << NPB_SHIFT) + t;
    if (node < N_NODES) offsets[node] = ebeg + excl;
    if (b == (int)gridDim.x - 1 && t == 0) offsets[N_NODES] = N_EDGES;
    __syncthreads();

    // scatter from registers into block-exclusive CSR region
    #pragma unroll
    for (int i = 0; i < FINE_PE; ++i) {
        const int e = ebeg + t + i * NPB;
        if (e < eend) {
            const int pos = atomicAdd(&cur[pay[i].x >> 17], 1);
            sedge[pos] = make_int2(pay[i].x & 0x1FFFF, pay[i].y);
        }
    }
}

// ---------------------------------------------------------------------------
// fma 8 bf16 elements (packed in a uint4) into a[0..7]
// ---------------------------------------------------------------------------
__device__ __forceinline__ void acc8(float* a, uint4 v, float m) {
    const unsigned int u[4] = {v.x, v.y, v.z, v.w};
    #pragma unroll
    for (int i = 0; i < 4; ++i) {
        const float lo = __uint_as_float(u[i] << 16);
        const float hi = __uint_as_float(u[i] & 0xFFFF0000u);
        a[2 * i]     += m * lo;
        a[2 * i + 1] += m * hi;
    }
}

// ---------------------------------------------------------------------------
// Gather-accumulate (bf16). One wave per node, 4 slot-phases of 16 lanes.
// Processes nodes [node_beg, node_end).
// ---------------------------------------------------------------------------
__global__ void fagcn_gather_bf16(const ushort* __restrict__ xh,
                                  const int*   __restrict__ offsets,
                                  const int2*  __restrict__ sedge,
                                  float*       __restrict__ out,
                                  int node_beg, int node_end) {
    const int wave = node_beg + (int)((blockIdx.x * blockDim.x + threadIdx.x) >> 6);
    const int lane = (int)(threadIdx.x & 63);
    if (wave >= node_end) return;

    const int beg = offsets[wave];
    const int end = offsets[wave + 1];
    const int q   = lane >> 4;
    const int ql  = lane & 15;

    float a[8] = {0.f, 0.f, 0.f, 0.f, 0.f, 0.f, 0.f, 0.f};
    float b[8] = {0.f, 0.f, 0.f, 0.f, 0.f, 0.f, 0.f, 0.f};

    int e = beg + q;
    for (; e + 12 < end; e += 16) {
        const int2 ed0 = sedge[e];
        const int2 ed1 = sedge[e + 4];
        const int2 ed2 = sedge[e + 8];
        const int2 ed3 = sedge[e + 12];
        const uint4 v0 = *reinterpret_cast<const uint4*>(xh + (size_t)ed0.x * HIDDEN + ql * 8);
        const uint4 v1 = *reinterpret_cast<const uint4*>(xh + (size_t)ed1.x * HIDDEN + ql * 8);
        const uint4 v2 = *reinterpret_cast<const uint4*>(xh + (size_t)ed2.x * HIDDEN + ql * 8);
        const uint4 v3 = *reinterpret_cast<const uint4*>(xh + (size_t)ed3.x * HIDDEN + ql * 8);
        acc8(a, v0, __int_as_float(ed0.y));
        acc8(b, v1, __int_as_float(ed1.y));
        acc8(a, v2, __int_as_float(ed2.y));
        acc8(b, v3, __int_as_float(ed3.y));
    }
    for (; e < end; e += 4) {
        const int2 ed = sedge[e];
        const uint4 v = *reinterpret_cast<const uint4*>(xh + (size_t)ed.x * HIDDEN + ql * 8);
        acc8(a, v, __int_as_float(ed.y));
    }

    float r[8];
    #pragma unroll
    for (int i = 0; i < 8; ++i) r[i] = a[i] + b[i];
    #pragma unroll
    for (int i = 0; i < 8; ++i) r[i] += __shfl(r[i], lane ^ 16, 64);
    #pragma unroll
    for (int i = 0; i < 8; ++i) r[i] += __shfl(r[i], lane ^ 32, 64);

    if (lane < 16) {
        float* o = out + (size_t)wave * HIDDEN + ql * 8;
        float4 lo = {r[0], r[1], r[2], r[3]};
        float4 hi = {r[4], r[5], r[6], r[7]};
        *reinterpret_cast<float4*>(o)     = lo;
        *reinterpret_cast<float4*>(o + 4) = hi;
    }
}

// ===========================================================================
// Fallback path (round-6 structure) — used only if workspace is too small.
// ===========================================================================
__global__ void fagcn_hist(const int* __restrict__ in_idx,
                           int* __restrict__ counts) {
    const int e = blockIdx.x * blockDim.x + threadIdx.x;
    if (e < N_EDGES) atomicAdd(&counts[in_idx[e]], 1);
}

__global__ void fagcn_zero_nodes(int* __restrict__ counts) {
    const int i = blockIdx.x * blockDim.x + threadIdx.x;
    if (i < N_NODES) counts[i] = 0;
}

__global__ void fagcn_scan1(const int* __restrict__ counts,
                            int* __restrict__ tsum) {
    const int t = blockIdx.x * blockDim.x + threadIdx.x;
    if (t >= SCAN_THREADS) return;
    int s = 0;
    if (t < SCAN_T) {
        const int beg = t * SCAN_C;
        const int end = (beg + SCAN_C < N_NODES) ? beg + SCAN_C : N_NODES;
        for (int i = beg; i < end; ++i) s += counts[i];
    }
    tsum[t] = s;
}

__global__ void fagcn_scan2(int* __restrict__ tsum) {
    __shared__ int lsum[1024];
    const int t = (int)threadIdx.x;
    const int C = (SCAN_THREADS + 1023) / 1024;
    const int beg = t * C;
    const int end = (beg + C < SCAN_THREADS) ? beg + C : SCAN_THREADS;
    int s = 0;
    for (int i = beg; i < end; ++i) s += tsum[i];
    lsum[t] = s;
    __syncthreads();
    for (int off = 1; off < 1024; off <<= 1) {
        int v = (t >= off) ? lsum[t - off] : 0;
        __syncthreads();
        lsum[t] += v;
        __syncthreads();
    }
    int prefix = (t == 0) ? 0 : lsum[t - 1];
    for (int i = beg; i < end; ++i) {
        const int v = tsum[i];
        tsum[i] = prefix;
        prefix += v;
    }
}

__global__ void fagcn_scan3(int* counts,
                            const int* __restrict__ tsum,
                            int* __restrict__ offsets) {
    const int t = blockIdx.x * blockDim.x + threadIdx.x;
    if (t >= SCAN_T) return;
    const int beg = t * SCAN_C;
    const int end = (beg + SCAN_C < N_NODES) ? beg + SCAN_C : N_NODES;
    int prefix = tsum[t];
    for (int i = beg; i < end; ++i) {
        const int c = counts[i];
        offsets[i] = prefix;
        prefix += c;
        counts[i] = 0;
    }
    if (t == 0) offsets[N_NODES] = N_EDGES;
}

__global__ void fagcn_bin(const float* __restrict__ adj,
                          const int*   __restrict__ in_idx,
                          const int*   __restrict__ out_idx,
                          const float* __restrict__ g1,
                          const float* __restrict__ g2,
                          const int*   __restrict__ offsets,
                          int*         __restrict__ cursor,
                          int2*        __restrict__ sedge) {
    const int e = blockIdx.x * blockDim.x + threadIdx.x;
    if (e >= N_EDGES) return;
    const int src = in_idx[e];
    const int dst = out_idx[e];
    const float m = tanhf(g1[src] + g2[dst]) * adj[e];
    const int pos = offsets[src] + atomicAdd(&cursor[src], 1);
    sedge[pos] = make_int2(dst, __float_as_int(m));
}

__global__ void fagcn_gather_f32(const float* __restrict__ x,
                                 const int*   __restrict__ offsets,
                                 const int2*  __restrict__ sedge,
                                 float*       __restrict__ out) {
    const int wave = (int)((blockIdx.x * blockDim.x + threadIdx.x) >> 6);
    const int lane = (int)(threadIdx.x & 63);
    if (wave >= N_NODES) return;
    const int beg  = offsets[wave];
    const int end  = offsets[wave + 1];
    const int half = lane >> 5;
    const int hl   = lane & 31;
    float4 a0 = {0.f, 0.f, 0.f, 0.f};
    float4 a1 = {0.f, 0.f, 0.f, 0.f};
    int e = beg + half;
    for (; e + 2 < end; e += 4) {
        const int2 ed0 = sedge[e];
        const int2 ed1 = sedge[e + 2];
        const float m0 = __int_as_float(ed0.y);
        const float m1 = __int_as_float(ed1.y);
        const float4 v0 = *reinterpret_cast<const float4*>(x + (size_t)ed0.x * HIDDEN + hl * 4);
        const float4 v1 = *reinterpret_cast<const float4*>(x + (size_t)ed1.x * HIDDEN + hl * 4);
        a0.x += m0 * v0.x; a0.y += m0 * v0.y; a0.z += m0 * v0.z; a0.w += m0 * v0.w;
        a1.x += m1 * v1.x; a1.y += m1 * v1.y; a1.z += m1 * v1.z; a1.w += m1 * v1.w;
    }
    for (; e < end; e += 2) {
        const int2 ed = sedge[e];
        const float m = __int_as_float(ed.y);
        const float4 v = *reinterpret_cast<const float4*>(x + (size_t)ed.x * HIDDEN + hl * 4);
        a0.x += m * v.x; a0.y += m * v.y; a0.z += m * v.z; a0.w += m * v.w;
    }
    float4 a;
    a.x = a0.x + a1.x; a.y = a0.y + a1.y; a.z = a0.z + a1.z; a.w = a0.w + a1.w;
    a.x += __shfl(a.x, lane ^ 32, 64);
    a.y += __shfl(a.y, lane ^ 32, 64);
    a.z += __shfl(a.z, lane ^ 32, 64);
    a.w += __shfl(a.w, lane ^ 32, 64);
    if (half == 0) {
        *reinterpret_cast<float4*>(out + (size_t)wave * HIDDEN + hl * 4) = a;
    }
}

extern "C" void kernel_launch(void* const* d_in, const int* in_sizes, int n_in,
                              void* d_out, int out_size, void* d_ws, size_t ws_size,
                              hipStream_t stream) {
    const float* x        = (const float*)d_in[0];
    const float* w1       = (const float*)d_in[1];
    const float* w2       = (const float*)d_in[2];
    const float* adj_vals = (const float*)d_in[3];
    const int*   in_idx   = (const int*)d_in[4];
    const int*   out_idx  = (const int*)d_in[5];
    float* out = (float*)d_out;

    // workspace layout
    ushort* xh      = (ushort*)d_ws;                              // 25.6 MB
    int2*   sedge   = (int2*)(xh + (size_t)N_NODES * HIDDEN);     // 12.8 MB
    int2*   stage   = sedge + N_EDGES;                            // 12.8 MB
    float*  g1      = (float*)(stage + N_EDGES);                  // 0.4 MB
    float*  g2      = g1 + N_NODES;                               // 0.4 MB
    int*    offsets = (int*)(g2 + N_NODES);                       // 0.4 MB
    int*    cursor  = offsets + N_NODES + 1;                      // 0.4 MB (fallback)
    int*    tsum    = cursor + N_NODES;                           // 25.6 KB (fallback)
    int*    bcnt    = tsum + SCAN_THREADS;                        // NB
    int*    sbase   = bcnt + NB;                                  // NB+1
    int*    bcur    = sbase + NB + 1;                             // NB

    const size_t need_full = (size_t)((char*)(bcur + NB) - (char*)d_ws);
    const size_t need_old  = need_full - (size_t)N_EDGES * 8;     // without stage
    const int full_path = (ws_size >= need_full);
    const int bf16_ok   = (ws_size >= need_old);

    if (full_path) {
        // zero bucket counters (tiny kernel, not rocclr fill)
        fagcn_zero<<<1, 256, 0, stream>>>(bcnt);
        // fused gates + bucket histogram
        fagcn_gates_hist<<<GATES_B + HIST_B, 256, 0, stream>>>(
            x, w1, w2, in_idx, g1, g2, bcnt, xh, 1, 1);
        // bucket exclusive scan (also zeroes bcur)
        fagcn_scanb<<<1, 256, 0, stream>>>(bcnt, sbase, bcur);
        // partition: 261 blocks x 512 thr -> full CU coverage, 51K boundaries
        fagcn_part<<<PART_B, PART_T, 0, stream>>>(
            adj_vals, in_idx, out_idx, g1, g2, sbase, bcur, stage);
        // fine binning (single pass, payload in registers)
        fagcn_fine<<<NB, NPB, 0, stream>>>(stage, sbase, offsets, sedge);
        // gather in two halves (profiler visibility + smaller dispatch tail)
        const int half_nodes = N_NODES / 2;                       // 50000
        fagcn_gather_bf16<<<(half_nodes + 3) / 4, 256, 0, stream>>>(
            xh, offsets, sedge, out, 0, half_nodes);
        fagcn_gather_bf16<<<(N_NODES - half_nodes + 3) / 4, 256, 0, stream>>>(
            xh, offsets, sedge, out, half_nodes, N_NODES);
    } else {
        // legacy path (round-6 structure)
        if (!bf16_ok) sedge = (int2*)d_ws;
        fagcn_gates_hist<<<GATES_B, 256, 0, stream>>>(
            x, w1, w2, in_idx, g1, g2, bcnt, xh, bf16_ok, 0);
        fagcn_zero_nodes<<<(N_NODES + 255) / 256, 256, 0, stream>>>(cursor);
        fagcn_hist<<<(N_EDGES + 255) / 256, 256, 0, stream>>>(in_idx, cursor);
        fagcn_scan1<<<SCAN_B, 256, 0, stream>>>(cursor, tsum);
        fagcn_scan2<<<1, 1024, 0, stream>>>(tsum);
        fagcn_scan3<<<SCAN_B, 256, 0, stream>>>(cursor, tsum, offsets);
        fagcn_bin<<<(N_EDGES + 255) / 256, 256, 0, stream>>>(
            adj_vals, in_idx, out_idx, g1, g2, offsets, cursor, sedge);
        if (bf16_ok) {
            fagcn_gather_bf16<<<(N_NODES + 3) / 4, 256, 0, stream>>>(
                xh, offsets, sedge, out, 0, N_NODES);
        } else {
            fagcn_gather_f32<<<(N_NODES + 3) / 4, 256, 0, stream>>>(
                x, offsets, sedge, out);
        }
    }
}

// Round 14
// 159.556 us; speedup vs baseline: 1.0807x; 1.0807x over previous
//
#include <hip/hip_runtime.h>

#define N_NODES 100000
#define N_EDGES 1600000
#define HIDDEN  128

// bucket partition geometry (R12 best-measured config)
#define NPB_SHIFT 9
#define NPB       512                                   // nodes per bucket
#define NB        ((N_NODES + NPB - 1) / NPB)           // 196 buckets
#define PART_T    512                                   // threads per part block
#define PART_EPT  16                                    // edges per thread
#define PART_EPB  (PART_T * PART_EPT)                   // 8192 edges per block
#define PART_B    ((N_EDGES + PART_EPB - 1) / PART_EPB) // 196 blocks
#define HIST_EPT  16
#define HIST_EPB  (256 * HIST_EPT)                      // 4096
#define HIST_B    ((N_EDGES + HIST_EPB - 1) / HIST_EPB) // 391
#define GATES_B   ((N_NODES * 32 + 255) / 256)          // 12500 blocks
#define FINE_PE   20                                    // regs/thread in fine

// legacy-scan geometry (fallback path only)
#define SCAN_C 16
#define SCAN_T ((N_NODES + SCAN_C - 1) / SCAN_C)
#define SCAN_THREADS 6400
#define SCAN_B (SCAN_THREADS / 256)

// float -> bf16 round-to-nearest-even
__device__ __forceinline__ ushort f2bf(float f) {
    unsigned int u = __float_as_uint(f);
    u = (u + 0x7FFFu + ((u >> 16) & 1u)) >> 16;
    return (ushort)u;
}

// ---------------------------------------------------------------------------
// Tiny zero kernel: bcnt[NB] = 0
// ---------------------------------------------------------------------------
__global__ void fagcn_zero(int* __restrict__ bcnt) {
    const int t = (int)threadIdx.x;
    if (t < NB) bcnt[t] = 0;
}

// ---------------------------------------------------------------------------
// Fused kernel: blocks [0, GATES_B) do per-node gates (+bf16 x copy);
// blocks [GATES_B, GATES_B+HIST_B) do the bucket histogram of in_idx.
// ---------------------------------------------------------------------------
__global__ void fagcn_gates_hist(const float* __restrict__ x,
                                 const float* __restrict__ w1,
                                 const float* __restrict__ w2,
                                 const int*   __restrict__ in_idx,
                                 float* __restrict__ g1,
                                 float* __restrict__ g2,
                                 int*   __restrict__ bcnt,
                                 ushort* __restrict__ xh,
                                 int write_xh,
                                 int with_hist) {
    __shared__ int cnt[NB];
    if ((int)blockIdx.x < GATES_B) {
        // ---- gates role ----
        const int tid  = blockIdx.x * 256 + (int)threadIdx.x;
        const int node = tid >> 5;                 // 32 lanes per node
        const int hl   = (int)(threadIdx.x & 31);
        if (node >= N_NODES) return;

        const float4 xv  = *reinterpret_cast<const float4*>(x  + (size_t)node * HIDDEN + hl * 4);
        const float4 w1v = *reinterpret_cast<const float4*>(w1 + hl * 4);
        const float4 w2v = *reinterpret_cast<const float4*>(w2 + hl * 4);

        if (write_xh) {
            ushort4 h;
            h.x = f2bf(xv.x); h.y = f2bf(xv.y); h.z = f2bf(xv.z); h.w = f2bf(xv.w);
            *reinterpret_cast<ushort4*>(xh + (size_t)node * HIDDEN + hl * 4) = h;
        }

        float s1 = xv.x * w1v.x + xv.y * w1v.y + xv.z * w1v.z + xv.w * w1v.w;
        float s2 = xv.x * w2v.x + xv.y * w2v.y + xv.z * w2v.z + xv.w * w2v.w;

        #pragma unroll
        for (int off = 16; off > 0; off >>= 1) {
            s1 += __shfl_down(s1, off, 32);
            s2 += __shfl_down(s2, off, 32);
        }
        if (hl == 0) { g1[node] = s1; g2[node] = s2; }
    } else if (with_hist) {
        // ---- bucket histogram role ----
        const int tid  = (int)threadIdx.x;
        const int base = ((int)blockIdx.x - GATES_B) * HIST_EPB + tid * HIST_EPT;
        for (int j = tid; j < NB; j += 256) cnt[j] = 0;
        __syncthreads();
        if (base < N_EDGES) {                      // N_EDGES % HIST_EPT == 0
            #pragma unroll
            for (int i = 0; i < 4; ++i) {
                const int4 v = *reinterpret_cast<const int4*>(in_idx + base + i * 4);
                atomicAdd(&cnt[v.x >> NPB_SHIFT], 1);
                atomicAdd(&cnt[v.y >> NPB_SHIFT], 1);
                atomicAdd(&cnt[v.z >> NPB_SHIFT], 1);
                atomicAdd(&cnt[v.w >> NPB_SHIFT], 1);
            }
        }
        __syncthreads();
        for (int j = tid; j < NB; j += 256)
            if (cnt[j]) atomicAdd(&bcnt[j], cnt[j]);
    }
}

// ---------------------------------------------------------------------------
// Bucket scan: exclusive scan of NB bucket counts -> sbase (1 tiny block);
// sbase[NB] = N_EDGES; zeroes bcur.
// ---------------------------------------------------------------------------
__global__ void fagcn_scanb(const int* __restrict__ bcnt,
                            int* __restrict__ sbase,
                            int* __restrict__ bcur) {
    __shared__ int l[256];
    const int t = (int)threadIdx.x;
    const int c = (t < NB) ? bcnt[t] : 0;
    l[t] = c;
    __syncthreads();
    for (int off = 1; off < 256; off <<= 1) {
        int v = (t >= off) ? l[t - off] : 0;
        __syncthreads();
        l[t] += v;
        __syncthreads();
    }
    if (t < NB) { sbase[t] = l[t] - c; bcur[t] = 0; }
    if (t == NB - 1) sbase[NB] = l[t];             // == N_EDGES
}

// ---------------------------------------------------------------------------
// Partition pass: NO gate math, NO g1/g2 gathers — payload is
// (slocal<<17 | dst, adj_bits). Minimal random ops per edge.
// ---------------------------------------------------------------------------
__global__ void fagcn_part(const float* __restrict__ adj,
                           const int*   __restrict__ in_idx,
                           const int*   __restrict__ out_idx,
                           const int*   __restrict__ sbase,
                           int*         __restrict__ bcur,
                           int2*        __restrict__ stage) {
    __shared__ int cnt[NB], lbase[NB], lcur[NB];
    const int tid  = (int)threadIdx.x;                 // 0..511
    const int base = blockIdx.x * PART_EPB + tid * PART_EPT;

    for (int j = tid; j < NB; j += PART_T) { cnt[j] = 0; lcur[j] = 0; }
    __syncthreads();

    int s[PART_EPT];
    const bool act = (base < N_EDGES);                 // N_EDGES % PART_EPT == 0
    if (act) {
        #pragma unroll
        for (int i = 0; i < PART_EPT / 4; ++i) {
            const int4 v = *reinterpret_cast<const int4*>(in_idx + base + i * 4);
            s[4 * i + 0] = v.x; s[4 * i + 1] = v.y;
            s[4 * i + 2] = v.z; s[4 * i + 3] = v.w;
        }
        #pragma unroll
        for (int i = 0; i < PART_EPT; ++i)
            atomicAdd(&cnt[s[i] >> NPB_SHIFT], 1);
    }
    __syncthreads();
    for (int j = tid; j < NB; j += PART_T)
        if (cnt[j] > 0) lbase[j] = sbase[j] + atomicAdd(&bcur[j], cnt[j]);
    __syncthreads();
    if (act) {
        #pragma unroll
        for (int i = 0; i < PART_EPT / 4; ++i) {
            const int4   d4 = *reinterpret_cast<const int4*>(out_idx + base + i * 4);
            const float4 a4 = *reinterpret_cast<const float4*>(adj + base + i * 4);
            const int   dd[4] = {d4.x, d4.y, d4.z, d4.w};
            const float aa[4] = {a4.x, a4.y, a4.z, a4.w};
            #pragma unroll
            for (int k = 0; k < 4; ++k) {
                const int src = s[4 * i + k];
                const int b   = src >> NPB_SHIFT;
                const int pos = lbase[b] + atomicAdd(&lcur[b], 1);
                stage[pos] = make_int2(((src & (NPB - 1)) << 17) | dd[k],
                                       __float_as_int(aa[k]));
            }
        }
    }
}

// ---------------------------------------------------------------------------
// Fine binning: one block per bucket, single pass (payload passthrough).
// ---------------------------------------------------------------------------
__global__ void fagcn_fine(const int2* __restrict__ stage,
                           const int*  __restrict__ sbase,
                           int*        __restrict__ offsets,
                           int2*       __restrict__ sedge) {
    __shared__ int cnt[NPB];
    __shared__ int cur[NPB];
    const int b = (int)blockIdx.x;
    const int t = (int)threadIdx.x;            // 0..511

    const int ebeg = sbase[b];
    const int eend = sbase[b + 1];

    cnt[t] = 0;
    __syncthreads();

    // load payload into registers + LDS per-node count
    int2 pay[FINE_PE];
    #pragma unroll
    for (int i = 0; i < FINE_PE; ++i) {
        const int e = ebeg + t + i * NPB;
        if (e < eend) {
            pay[i] = stage[e];
            atomicAdd(&cnt[(unsigned)pay[i].x >> 17], 1);
        }
    }
    __syncthreads();

    // exclusive scan over NPB node counts
    const int c = cnt[t];
    for (int off = 1; off < NPB; off <<= 1) {
        int v = (t >= off) ? cnt[t - off] : 0;
        __syncthreads();
        cnt[t] += v;
        __syncthreads();
    }
    const int excl = cnt[t] - c;
    cur[t] = ebeg + excl;
    const int node = (b << NPB_SHIFT) + t;
    if (node < N_NODES) offsets[node] = ebeg + excl;
    if (b == (int)gridDim.x - 1 && t == 0) offsets[N_NODES] = N_EDGES;
    __syncthreads();

    // scatter (dst, adj) from registers into block-exclusive CSR region
    #pragma unroll
    for (int i = 0; i < FINE_PE; ++i) {
        const int e = ebeg + t + i * NPB;
        if (e < eend) {
            const int pos = atomicAdd(&cur[(unsigned)pay[i].x >> 17], 1);
            sedge[pos] = make_int2(pay[i].x & 0x1FFFF, pay[i].y);
        }
    }
}

// ---------------------------------------------------------------------------
// fma 8 bf16 elements (packed in a uint4) into a[0..7]
// ---------------------------------------------------------------------------
__device__ __forceinline__ void acc8(float* a, uint4 v, float m) {
    const unsigned int u[4] = {v.x, v.y, v.z, v.w};
    #pragma unroll
    for (int i = 0; i < 4; ++i) {
        const float lo = __uint_as_float(u[i] << 16);
        const float hi = __uint_as_float(u[i] & 0xFFFF0000u);
        a[2 * i]     += m * lo;
        a[2 * i + 1] += m * hi;
    }
}

// ---------------------------------------------------------------------------
// Gather-accumulate (bf16) WITH inline gate: m = tanh(g1[node]+g2[dst])*adj.
// g1[node] wave-uniform; g2[dst] broadcast load from L2-resident table.
// One wave per node, 4 slot-phases of 16 lanes; [node_beg, node_end).
// ---------------------------------------------------------------------------
__global__ void fagcn_gather_bf16(const ushort* __restrict__ xh,
                                  const float* __restrict__ g1,
                                  const float* __restrict__ g2,
                                  const int*   __restrict__ offsets,
                                  const int2*  __restrict__ sedge,
                                  float*       __restrict__ out,
                                  int node_beg, int node_end) {
    const int wave = node_beg + (int)((blockIdx.x * blockDim.x + threadIdx.x) >> 6);
    const int lane = (int)(threadIdx.x & 63);
    if (wave >= node_end) return;

    const int beg = offsets[wave];
    const int end = offsets[wave + 1];
    const int q   = lane >> 4;
    const int ql  = lane & 15;
    const float g1w = g1[wave];

    float a[8] = {0.f, 0.f, 0.f, 0.f, 0.f, 0.f, 0.f, 0.f};
    float b[8] = {0.f, 0.f, 0.f, 0.f, 0.f, 0.f, 0.f, 0.f};

    int e = beg + q;
    for (; e + 12 < end; e += 16) {
        const int2 ed0 = sedge[e];
        const int2 ed1 = sedge[e + 4];
        const int2 ed2 = sedge[e + 8];
        const int2 ed3 = sedge[e + 12];
        const float G0 = g2[ed0.x];
        const float G1 = g2[ed1.x];
        const float G2 = g2[ed2.x];
        const float G3 = g2[ed3.x];
        const uint4 v0 = *reinterpret_cast<const uint4*>(xh + (size_t)ed0.x * HIDDEN + ql * 8);
        const uint4 v1 = *reinterpret_cast<const uint4*>(xh + (size_t)ed1.x * HIDDEN + ql * 8);
        const uint4 v2 = *reinterpret_cast<const uint4*>(xh + (size_t)ed2.x * HIDDEN + ql * 8);
        const uint4 v3 = *reinterpret_cast<const uint4*>(xh + (size_t)ed3.x * HIDDEN + ql * 8);
        acc8(a, v0, tanhf(g1w + G0) * __int_as_float(ed0.y));
        acc8(b, v1, tanhf(g1w + G1) * __int_as_float(ed1.y));
        acc8(a, v2, tanhf(g1w + G2) * __int_as_float(ed2.y));
        acc8(b, v3, tanhf(g1w + G3) * __int_as_float(ed3.y));
    }
    for (; e < end; e += 4) {
        const int2 ed = sedge[e];
        const float m = tanhf(g1w + g2[ed.x]) * __int_as_float(ed.y);
        const uint4 v = *reinterpret_cast<const uint4*>(xh + (size_t)ed.x * HIDDEN + ql * 8);
        acc8(a, v, m);
    }

    float r[8];
    #pragma unroll
    for (int i = 0; i < 8; ++i) r[i] = a[i] + b[i];
    #pragma unroll
    for (int i = 0; i < 8; ++i) r[i] += __shfl(r[i], lane ^ 16, 64);
    #pragma unroll
    for (int i = 0; i < 8; ++i) r[i] += __shfl(r[i], lane ^ 32, 64);

    if (lane < 16) {
        float* o = out + (size_t)wave * HIDDEN + ql * 8;
        float4 lo = {r[0], r[1], r[2], r[3]};
        float4 hi = {r[4], r[5], r[6], r[7]};
        *reinterpret_cast<float4*>(o)     = lo;
        *reinterpret_cast<float4*>(o + 4) = hi;
    }
}

// ===========================================================================
// Fallback path — used only if workspace is too small. (dst, adj) semantics.
// ===========================================================================
__global__ void fagcn_hist(const int* __restrict__ in_idx,
                           int* __restrict__ counts) {
    const int e = blockIdx.x * blockDim.x + threadIdx.x;
    if (e < N_EDGES) atomicAdd(&counts[in_idx[e]], 1);
}

__global__ void fagcn_zero_nodes(int* __restrict__ counts) {
    const int i = blockIdx.x * blockDim.x + threadIdx.x;
    if (i < N_NODES) counts[i] = 0;
}

__global__ void fagcn_scan1(const int* __restrict__ counts,
                            int* __restrict__ tsum) {
    const int t = blockIdx.x * blockDim.x + threadIdx.x;
    if (t >= SCAN_THREADS) return;
    int s = 0;
    if (t < SCAN_T) {
        const int beg = t * SCAN_C;
        const int end = (beg + SCAN_C < N_NODES) ? beg + SCAN_C : N_NODES;
        for (int i = beg; i < end; ++i) s += counts[i];
    }
    tsum[t] = s;
}

__global__ void fagcn_scan2(int* __restrict__ tsum) {
    __shared__ int lsum[1024];
    const int t = (int)threadIdx.x;
    const int C = (SCAN_THREADS + 1023) / 1024;
    const int beg = t * C;
    const int end = (beg + C < SCAN_THREADS) ? beg + C : SCAN_THREADS;
    int s = 0;
    for (int i = beg; i < end; ++i) s += tsum[i];
    lsum[t] = s;
    __syncthreads();
    for (int off = 1; off < 1024; off <<= 1) {
        int v = (t >= off) ? lsum[t - off] : 0;
        __syncthreads();
        lsum[t] += v;
        __syncthreads();
    }
    int prefix = (t == 0) ? 0 : lsum[t - 1];
    for (int i = beg; i < end; ++i) {
        const int v = tsum[i];
        tsum[i] = prefix;
        prefix += v;
    }
}

__global__ void fagcn_scan3(int* counts,
                            const int* __restrict__ tsum,
                            int* __restrict__ offsets) {
    const int t = blockIdx.x * blockDim.x + threadIdx.x;
    if (t >= SCAN_T) return;
    const int beg = t * SCAN_C;
    const int end = (beg + SCAN_C < N_NODES) ? beg + SCAN_C : N_NODES;
    int prefix = tsum[t];
    for (int i = beg; i < end; ++i) {
        const int c = counts[i];
        offsets[i] = prefix;
        prefix += c;
        counts[i] = 0;
    }
    if (t == 0) offsets[N_NODES] = N_EDGES;
}

__global__ void fagcn_bin(const float* __restrict__ adj,
                          const int*   __restrict__ in_idx,
                          const int*   __restrict__ out_idx,
                          const int*   __restrict__ offsets,
                          int*         __restrict__ cursor,
                          int2*        __restrict__ sedge) {
    const int e = blockIdx.x * blockDim.x + threadIdx.x;
    if (e >= N_EDGES) return;
    const int src = in_idx[e];
    const int pos = offsets[src] + atomicAdd(&cursor[src], 1);
    sedge[pos] = make_int2(out_idx[e], __float_as_int(adj[e]));
}

__global__ void fagcn_gather_f32(const float* __restrict__ x,
                                 const float* __restrict__ g1,
                                 const float* __restrict__ g2,
                                 const int*   __restrict__ offsets,
                                 const int2*  __restrict__ sedge,
                                 float*       __restrict__ out) {
    const int wave = (int)((blockIdx.x * blockDim.x + threadIdx.x) >> 6);
    const int lane = (int)(threadIdx.x & 63);
    if (wave >= N_NODES) return;
    const int beg  = offsets[wave];
    const int end  = offsets[wave + 1];
    const int half = lane >> 5;
    const int hl   = lane & 31;
    const float g1w = g1[wave];
    float4 a0 = {0.f, 0.f, 0.f, 0.f};
    float4 a1 = {0.f, 0.f, 0.f, 0.f};
    int e = beg + half;
    for (; e + 2 < end; e += 4) {
        const int2 ed0 = sedge[e];
        const int2 ed1 = sedge[e + 2];
        const float m0 = tanhf(g1w + g2[ed0.x]) * __int_as_float(ed0.y);
        const float m1 = tanhf(g1w + g2[ed1.x]) * __int_as_float(ed1.y);
        const float4 v0 = *reinterpret_cast<const float4*>(x + (size_t)ed0.x * HIDDEN + hl * 4);
        const float4 v1 = *reinterpret_cast<const float4*>(x + (size_t)ed1.x * HIDDEN + hl * 4);
        a0.x += m0 * v0.x; a0.y += m0 * v0.y; a0.z += m0 * v0.z; a0.w += m0 * v0.w;
        a1.x += m1 * v1.x; a1.y += m1 * v1.y; a1.z += m1 * v1.z; a1.w += m1 * v1.w;
    }
    for (; e < end; e += 2) {
        const int2 ed = sedge[e];
        const float m = tanhf(g1w + g2[ed.x]) * __int_as_float(ed.y);
        const float4 v = *reinterpret_cast<const float4*>(x + (size_t)ed.x * HIDDEN + hl * 4);
        a0.x += m * v.x; a0.y += m * v.y; a0.z += m * v.z; a0.w += m * v.w;
    }
    float4 a;
    a.x = a0.x + a1.x; a.y = a0.y + a1.y; a.z = a0.z + a1.z; a.w = a0.w + a1.w;
    a.x += __shfl(a.x, lane ^ 32, 64);
    a.y += __shfl(a.y, lane ^ 32, 64);
    a.z += __shfl(a.z, lane ^ 32, 64);
    a.w += __shfl(a.w, lane ^ 32, 64);
    if (half == 0) {
        *reinterpret_cast<float4*>(out + (size_t)wave * HIDDEN + hl * 4) = a;
    }
}

extern "C" void kernel_launch(void* const* d_in, const int* in_sizes, int n_in,
                              void* d_out, int out_size, void* d_ws, size_t ws_size,
                              hipStream_t stream) {
    const float* x        = (const float*)d_in[0];
    const float* w1       = (const float*)d_in[1];
    const float* w2       = (const float*)d_in[2];
    const float* adj_vals = (const float*)d_in[3];
    const int*   in_idx   = (const int*)d_in[4];
    const int*   out_idx  = (const int*)d_in[5];
    float* out = (float*)d_out;

    // workspace layout
    ushort* xh      = (ushort*)d_ws;                              // 25.6 MB
    int2*   sedge   = (int2*)(xh + (size_t)N_NODES * HIDDEN);     // 12.8 MB
    int2*   stage   = sedge + N_EDGES;                            // 12.8 MB
    float*  g1      = (float*)(stage + N_EDGES);                  // 0.4 MB
    float*  g2      = g1 + N_NODES;                               // 0.4 MB
    int*    offsets = (int*)(g2 + N_NODES);                       // 0.4 MB
    int*    cursor  = offsets + N_NODES + 1;                      // 0.4 MB (fallback)
    int*    tsum    = cursor + N_NODES;                           // 25.6 KB (fallback)
    int*    bcnt    = tsum + SCAN_THREADS;                        // NB
    int*    sbase   = bcnt + NB;                                  // NB+1
    int*    bcur    = sbase + NB + 1;                             // NB

    const size_t need_full = (size_t)((char*)(bcur + NB) - (char*)d_ws);
    const size_t need_old  = need_full - (size_t)N_EDGES * 8;     // without stage
    const int full_path = (ws_size >= need_full);
    const int bf16_ok   = (ws_size >= need_old);

    if (full_path) {
        // zero bucket counters
        fagcn_zero<<<1, 256, 0, stream>>>(bcnt);
        // fused gates + bucket histogram
        fagcn_gates_hist<<<GATES_B + HIST_B, 256, 0, stream>>>(
            x, w1, w2, in_idx, g1, g2, bcnt, xh, 1, 1);
        // bucket exclusive scan (also zeroes bcur)
        fagcn_scanb<<<1, 256, 0, stream>>>(bcnt, sbase, bcur);
        // partition: gate-free, minimal random ops per edge
        fagcn_part<<<PART_B, PART_T, 0, stream>>>(
            adj_vals, in_idx, out_idx, sbase, bcur, stage);
        // fine binning (payload passthrough)
        fagcn_fine<<<NB, NPB, 0, stream>>>(stage, sbase, offsets, sedge);
        // gather with inline gate, in two halves
        const int half_nodes = N_NODES / 2;                       // 50000
        fagcn_gather_bf16<<<(half_nodes + 3) / 4, 256, 0, stream>>>(
            xh, g1, g2, offsets, sedge, out, 0, half_nodes);
        fagcn_gather_bf16<<<(N_NODES - half_nodes + 3) / 4, 256, 0, stream>>>(
            xh, g1, g2, offsets, sedge, out, half_nodes, N_NODES);
    } else {
        // legacy path
        if (!bf16_ok) sedge = (int2*)d_ws;
        fagcn_gates_hist<<<GATES_B, 256, 0, stream>>>(
            x, w1, w2, in_idx, g1, g2, bcnt, xh, bf16_ok, 0);
        fagcn_zero_nodes<<<(N_NODES + 255) / 256, 256, 0, stream>>>(cursor);
        fagcn_hist<<<(N_EDGES + 255) / 256, 256, 0, stream>>>(in_idx, cursor);
        fagcn_scan1<<<SCAN_B, 256, 0, stream>>>(cursor, tsum);
        fagcn_scan2<<<1, 1024, 0, stream>>>(tsum);
        fagcn_scan3<<<SCAN_B, 256, 0, stream>>>(cursor, tsum, offsets);
        fagcn_bin<<<(N_EDGES + 255) / 256, 256, 0, stream>>>(
            adj_vals, in_idx, out_idx, offsets, cursor, sedge);
        if (bf16_ok) {
            fagcn_gather_bf16<<<(N_NODES + 3) / 4, 256, 0, stream>>>(
                xh, g1, g2, offsets, sedge, out, 0, N_NODES);
        } else {
            fagcn_gather_f32<<<(N_NODES + 3) / 4, 256, 0, stream>>>(
                x, g1, g2, offsets, sedge, out);
        }
    }
}

// Round 15
// 149.901 us; speedup vs baseline: 1.1504x; 1.0644x over previous
//
#include <hip/hip_runtime.h>

#define N_NODES 100000
#define N_EDGES 1600000
#define HIDDEN  128

// bucket partition geometry (R12 best-measured config)
#define NPB_SHIFT 9
#define NPB       512                                   // nodes per bucket
#define NB        ((N_NODES + NPB - 1) / NPB)           // 196 buckets
#define PART_T    512                                   // threads per part block
#define PART_EPT  16                                    // edges per thread
#define PART_EPB  (PART_T * PART_EPT)                   // 8192 edges per block
#define PART_B    ((N_EDGES + PART_EPB - 1) / PART_EPB) // 196 blocks
#define HIST_EPT  16
#define HIST_EPB  (256 * HIST_EPT)                      // 4096
#define HIST_B    ((N_EDGES + HIST_EPB - 1) / HIST_EPB) // 391
#define GATES_B   ((N_NODES * 32 + 255) / 256)          // 12500 blocks
#define FINE_PE   20                                    // regs/thread in fine

// legacy-scan geometry (fallback path only)
#define SCAN_C 16
#define SCAN_T ((N_NODES + SCAN_C - 1) / SCAN_C)
#define SCAN_THREADS 6400
#define SCAN_B (SCAN_THREADS / 256)

// float -> bf16 round-to-nearest-even
__device__ __forceinline__ ushort f2bf(float f) {
    unsigned int u = __float_as_uint(f);
    u = (u + 0x7FFFu + ((u >> 16) & 1u)) >> 16;
    return (ushort)u;
}

// ---------------------------------------------------------------------------
// Tiny zero kernel: bcnt[NB] = 0
// ---------------------------------------------------------------------------
__global__ void fagcn_zero(int* __restrict__ bcnt) {
    const int t = (int)threadIdx.x;
    if (t < NB) bcnt[t] = 0;
}

// ---------------------------------------------------------------------------
// Fused kernel: blocks [0, GATES_B) do per-node gates (+bf16 x copy);
// blocks [GATES_B, GATES_B+HIST_B) do the bucket histogram of in_idx.
// ---------------------------------------------------------------------------
__global__ void fagcn_gates_hist(const float* __restrict__ x,
                                 const float* __restrict__ w1,
                                 const float* __restrict__ w2,
                                 const int*   __restrict__ in_idx,
                                 float* __restrict__ g1,
                                 float* __restrict__ g2,
                                 int*   __restrict__ bcnt,
                                 ushort* __restrict__ xh,
                                 int write_xh,
                                 int with_hist) {
    __shared__ int cnt[NB];
    if ((int)blockIdx.x < GATES_B) {
        // ---- gates role ----
        const int tid  = blockIdx.x * 256 + (int)threadIdx.x;
        const int node = tid >> 5;                 // 32 lanes per node
        const int hl   = (int)(threadIdx.x & 31);
        if (node >= N_NODES) return;

        const float4 xv  = *reinterpret_cast<const float4*>(x  + (size_t)node * HIDDEN + hl * 4);
        const float4 w1v = *reinterpret_cast<const float4*>(w1 + hl * 4);
        const float4 w2v = *reinterpret_cast<const float4*>(w2 + hl * 4);

        if (write_xh) {
            ushort4 h;
            h.x = f2bf(xv.x); h.y = f2bf(xv.y); h.z = f2bf(xv.z); h.w = f2bf(xv.w);
            *reinterpret_cast<ushort4*>(xh + (size_t)node * HIDDEN + hl * 4) = h;
        }

        float s1 = xv.x * w1v.x + xv.y * w1v.y + xv.z * w1v.z + xv.w * w1v.w;
        float s2 = xv.x * w2v.x + xv.y * w2v.y + xv.z * w2v.z + xv.w * w2v.w;

        #pragma unroll
        for (int off = 16; off > 0; off >>= 1) {
            s1 += __shfl_down(s1, off, 32);
            s2 += __shfl_down(s2, off, 32);
        }
        if (hl == 0) { g1[node] = s1; g2[node] = s2; }
    } else if (with_hist) {
        // ---- bucket histogram role ----
        const int tid  = (int)threadIdx.x;
        const int base = ((int)blockIdx.x - GATES_B) * HIST_EPB + tid * HIST_EPT;
        for (int j = tid; j < NB; j += 256) cnt[j] = 0;
        __syncthreads();
        if (base < N_EDGES) {                      // N_EDGES % HIST_EPT == 0
            #pragma unroll
            for (int i = 0; i < 4; ++i) {
                const int4 v = *reinterpret_cast<const int4*>(in_idx + base + i * 4);
                atomicAdd(&cnt[v.x >> NPB_SHIFT], 1);
                atomicAdd(&cnt[v.y >> NPB_SHIFT], 1);
                atomicAdd(&cnt[v.z >> NPB_SHIFT], 1);
                atomicAdd(&cnt[v.w >> NPB_SHIFT], 1);
            }
        }
        __syncthreads();
        for (int j = tid; j < NB; j += 256)
            if (cnt[j]) atomicAdd(&bcnt[j], cnt[j]);
    }
}

// ---------------------------------------------------------------------------
// Bucket scan: exclusive scan of NB bucket counts -> sbase (1 tiny block);
// sbase[NB] = N_EDGES; zeroes bcur.
// ---------------------------------------------------------------------------
__global__ void fagcn_scanb(const int* __restrict__ bcnt,
                            int* __restrict__ sbase,
                            int* __restrict__ bcur) {
    __shared__ int l[256];
    const int t = (int)threadIdx.x;
    const int c = (t < NB) ? bcnt[t] : 0;
    l[t] = c;
    __syncthreads();
    for (int off = 1; off < 256; off <<= 1) {
        int v = (t >= off) ? l[t - off] : 0;
        __syncthreads();
        l[t] += v;
        __syncthreads();
    }
    if (t < NB) { sbase[t] = l[t] - c; bcur[t] = 0; }
    if (t == NB - 1) sbase[NB] = l[t];             // == N_EDGES
}

// ---------------------------------------------------------------------------
// Partition pass: gate-free — payload (slocal<<17 | dst, adj_bits).
// ---------------------------------------------------------------------------
__global__ void fagcn_part(const float* __restrict__ adj,
                           const int*   __restrict__ in_idx,
                           const int*   __restrict__ out_idx,
                           const int*   __restrict__ sbase,
                           int*         __restrict__ bcur,
                           int2*        __restrict__ stage) {
    __shared__ int cnt[NB], lbase[NB], lcur[NB];
    const int tid  = (int)threadIdx.x;                 // 0..511
    const int base = blockIdx.x * PART_EPB + tid * PART_EPT;

    for (int j = tid; j < NB; j += PART_T) { cnt[j] = 0; lcur[j] = 0; }
    __syncthreads();

    int s[PART_EPT];
    const bool act = (base < N_EDGES);                 // N_EDGES % PART_EPT == 0
    if (act) {
        #pragma unroll
        for (int i = 0; i < PART_EPT / 4; ++i) {
            const int4 v = *reinterpret_cast<const int4*>(in_idx + base + i * 4);
            s[4 * i + 0] = v.x; s[4 * i + 1] = v.y;
            s[4 * i + 2] = v.z; s[4 * i + 3] = v.w;
        }
        #pragma unroll
        for (int i = 0; i < PART_EPT; ++i)
            atomicAdd(&cnt[s[i] >> NPB_SHIFT], 1);
    }
    __syncthreads();
    for (int j = tid; j < NB; j += PART_T)
        if (cnt[j] > 0) lbase[j] = sbase[j] + atomicAdd(&bcur[j], cnt[j]);
    __syncthreads();
    if (act) {
        #pragma unroll
        for (int i = 0; i < PART_EPT / 4; ++i) {
            const int4   d4 = *reinterpret_cast<const int4*>(out_idx + base + i * 4);
            const float4 a4 = *reinterpret_cast<const float4*>(adj + base + i * 4);
            const int   dd[4] = {d4.x, d4.y, d4.z, d4.w};
            const float aa[4] = {a4.x, a4.y, a4.z, a4.w};
            #pragma unroll
            for (int k = 0; k < 4; ++k) {
                const int src = s[4 * i + k];
                const int b   = src >> NPB_SHIFT;
                const int pos = lbase[b] + atomicAdd(&lcur[b], 1);
                stage[pos] = make_int2(((src & (NPB - 1)) << 17) | dd[k],
                                       __float_as_int(aa[k]));
            }
        }
    }
}

// ---------------------------------------------------------------------------
// Fine binning WITH gate: lane-packed tanh. g1 for the bucket's 512 nodes
// staged in LDS; g2[dst] random load (L2-resident, FINE_PE-deep MLP).
// Writes final sedge payload (dst, m).
// ---------------------------------------------------------------------------
__global__ void fagcn_fine(const int2* __restrict__ stage,
                           const int*  __restrict__ sbase,
                           const float* __restrict__ g1,
                           const float* __restrict__ g2,
                           int*        __restrict__ offsets,
                           int2*       __restrict__ sedge) {
    __shared__ int cnt[NPB];
    __shared__ int cur[NPB];
    __shared__ float g1s[NPB];
    const int b = (int)blockIdx.x;
    const int t = (int)threadIdx.x;            // 0..511

    const int ebeg = sbase[b];
    const int eend = sbase[b + 1];
    const int node = (b << NPB_SHIFT) + t;

    g1s[t] = (node < N_NODES) ? g1[node] : 0.f;
    cnt[t] = 0;
    __syncthreads();

    // load payload into registers, issue g2 gathers (MLP), LDS per-node count
    int2  pay[FINE_PE];
    float gv[FINE_PE];
    #pragma unroll
    for (int i = 0; i < FINE_PE; ++i) {
        const int e = ebeg + t + i * NPB;
        if (e < eend) {
            pay[i] = stage[e];
            gv[i]  = g2[pay[i].x & 0x1FFFF];
            atomicAdd(&cnt[(unsigned)pay[i].x >> 17], 1);
        }
    }
    __syncthreads();

    // exclusive scan over NPB node counts
    const int c = cnt[t];
    for (int off = 1; off < NPB; off <<= 1) {
        int v = (t >= off) ? cnt[t - off] : 0;
        __syncthreads();
        cnt[t] += v;
        __syncthreads();
    }
    const int excl = cnt[t] - c;
    cur[t] = ebeg + excl;
    if (node < N_NODES) offsets[node] = ebeg + excl;
    if (b == (int)gridDim.x - 1 && t == 0) offsets[N_NODES] = N_EDGES;
    __syncthreads();

    // lane-packed gate + scatter into block-exclusive CSR region
    #pragma unroll
    for (int i = 0; i < FINE_PE; ++i) {
        const int e = ebeg + t + i * NPB;
        if (e < eend) {
            const int slocal = (unsigned)pay[i].x >> 17;
            const float m = tanhf(g1s[slocal] + gv[i]) * __int_as_float(pay[i].y);
            const int pos = atomicAdd(&cur[slocal], 1);
            sedge[pos] = make_int2(pay[i].x & 0x1FFFF, __float_as_int(m));
        }
    }
}

// ---------------------------------------------------------------------------
// fma 8 bf16 elements (packed in a uint4) into a[0..7]
// ---------------------------------------------------------------------------
__device__ __forceinline__ void acc8(float* a, uint4 v, float m) {
    const unsigned int u[4] = {v.x, v.y, v.z, v.w};
    #pragma unroll
    for (int i = 0; i < 4; ++i) {
        const float lo = __uint_as_float(u[i] << 16);
        const float hi = __uint_as_float(u[i] & 0xFFFF0000u);
        a[2 * i]     += m * lo;
        a[2 * i + 1] += m * hi;
    }
}

// ---------------------------------------------------------------------------
// Gather-accumulate (bf16), R12 form: m precomputed in sedge.
// One wave per node, 4 slot-phases of 16 lanes; [node_beg, node_end).
// ---------------------------------------------------------------------------
__global__ void fagcn_gather_bf16(const ushort* __restrict__ xh,
                                  const int*   __restrict__ offsets,
                                  const int2*  __restrict__ sedge,
                                  float*       __restrict__ out,
                                  int node_beg, int node_end) {
    const int wave = node_beg + (int)((blockIdx.x * blockDim.x + threadIdx.x) >> 6);
    const int lane = (int)(threadIdx.x & 63);
    if (wave >= node_end) return;

    const int beg = offsets[wave];
    const int end = offsets[wave + 1];
    const int q   = lane >> 4;
    const int ql  = lane & 15;

    float a[8] = {0.f, 0.f, 0.f, 0.f, 0.f, 0.f, 0.f, 0.f};
    float b[8] = {0.f, 0.f, 0.f, 0.f, 0.f, 0.f, 0.f, 0.f};

    int e = beg + q;
    for (; e + 12 < end; e += 16) {
        const int2 ed0 = sedge[e];
        const int2 ed1 = sedge[e + 4];
        const int2 ed2 = sedge[e + 8];
        const int2 ed3 = sedge[e + 12];
        const uint4 v0 = *reinterpret_cast<const uint4*>(xh + (size_t)ed0.x * HIDDEN + ql * 8);
        const uint4 v1 = *reinterpret_cast<const uint4*>(xh + (size_t)ed1.x * HIDDEN + ql * 8);
        const uint4 v2 = *reinterpret_cast<const uint4*>(xh + (size_t)ed2.x * HIDDEN + ql * 8);
        const uint4 v3 = *reinterpret_cast<const uint4*>(xh + (size_t)ed3.x * HIDDEN + ql * 8);
        acc8(a, v0, __int_as_float(ed0.y));
        acc8(b, v1, __int_as_float(ed1.y));
        acc8(a, v2, __int_as_float(ed2.y));
        acc8(b, v3, __int_as_float(ed3.y));
    }
    for (; e < end; e += 4) {
        const int2 ed = sedge[e];
        const uint4 v = *reinterpret_cast<const uint4*>(xh + (size_t)ed.x * HIDDEN + ql * 8);
        acc8(a, v, __int_as_float(ed.y));
    }

    float r[8];
    #pragma unroll
    for (int i = 0; i < 8; ++i) r[i] = a[i] + b[i];
    #pragma unroll
    for (int i = 0; i < 8; ++i) r[i] += __shfl(r[i], lane ^ 16, 64);
    #pragma unroll
    for (int i = 0; i < 8; ++i) r[i] += __shfl(r[i], lane ^ 32, 64);

    if (lane < 16) {
        float* o = out + (size_t)wave * HIDDEN + ql * 8;
        float4 lo = {r[0], r[1], r[2], r[3]};
        float4 hi = {r[4], r[5], r[6], r[7]};
        *reinterpret_cast<float4*>(o)     = lo;
        *reinterpret_cast<float4*>(o + 4) = hi;
    }
}

// ===========================================================================
// Fallback path (round-6 structure, m computed in bin) — small-ws only.
// ===========================================================================
__global__ void fagcn_hist(const int* __restrict__ in_idx,
                           int* __restrict__ counts) {
    const int e = blockIdx.x * blockDim.x + threadIdx.x;
    if (e < N_EDGES) atomicAdd(&counts[in_idx[e]], 1);
}

__global__ void fagcn_zero_nodes(int* __restrict__ counts) {
    const int i = blockIdx.x * blockDim.x + threadIdx.x;
    if (i < N_NODES) counts[i] = 0;
}

__global__ void fagcn_scan1(const int* __restrict__ counts,
                            int* __restrict__ tsum) {
    const int t = blockIdx.x * blockDim.x + threadIdx.x;
    if (t >= SCAN_THREADS) return;
    int s = 0;
    if (t < SCAN_T) {
        const int beg = t * SCAN_C;
        const int end = (beg + SCAN_C < N_NODES) ? beg + SCAN_C : N_NODES;
        for (int i = beg; i < end; ++i) s += counts[i];
    }
    tsum[t] = s;
}

__global__ void fagcn_scan2(int* __restrict__ tsum) {
    __shared__ int lsum[1024];
    const int t = (int)threadIdx.x;
    const int C = (SCAN_THREADS + 1023) / 1024;
    const int beg = t * C;
    const int end = (beg + C < SCAN_THREADS) ? beg + C : SCAN_THREADS;
    int s = 0;
    for (int i = beg; i < end; ++i) s += tsum[i];
    lsum[t] = s;
    __syncthreads();
    for (int off = 1; off < 1024; off <<= 1) {
        int v = (t >= off) ? lsum[t - off] : 0;
        __syncthreads();
        lsum[t] += v;
        __syncthreads();
    }
    int prefix = (t == 0) ? 0 : lsum[t - 1];
    for (int i = beg; i < end; ++i) {
        const int v = tsum[i];
        tsum[i] = prefix;
        prefix += v;
    }
}

__global__ void fagcn_scan3(int* counts,
                            const int* __restrict__ tsum,
                            int* __restrict__ offsets) {
    const int t = blockIdx.x * blockDim.x + threadIdx.x;
    if (t >= SCAN_T) return;
    const int beg = t * SCAN_C;
    const int end = (beg + SCAN_C < N_NODES) ? beg + SCAN_C : N_NODES;
    int prefix = tsum[t];
    for (int i = beg; i < end; ++i) {
        const int c = counts[i];
        offsets[i] = prefix;
        prefix += c;
        counts[i] = 0;
    }
    if (t == 0) offsets[N_NODES] = N_EDGES;
}

__global__ void fagcn_bin(const float* __restrict__ adj,
                          const int*   __restrict__ in_idx,
                          const int*   __restrict__ out_idx,
                          const float* __restrict__ g1,
                          const float* __restrict__ g2,
                          const int*   __restrict__ offsets,
                          int*         __restrict__ cursor,
                          int2*        __restrict__ sedge) {
    const int e = blockIdx.x * blockDim.x + threadIdx.x;
    if (e >= N_EDGES) return;
    const int src = in_idx[e];
    const int dst = out_idx[e];
    const float m = tanhf(g1[src] + g2[dst]) * adj[e];
    const int pos = offsets[src] + atomicAdd(&cursor[src], 1);
    sedge[pos] = make_int2(dst, __float_as_int(m));
}

__global__ void fagcn_gather_f32(const float* __restrict__ x,
                                 const int*   __restrict__ offsets,
                                 const int2*  __restrict__ sedge,
                                 float*       __restrict__ out) {
    const int wave = (int)((blockIdx.x * blockDim.x + threadIdx.x) >> 6);
    const int lane = (int)(threadIdx.x & 63);
    if (wave >= N_NODES) return;
    const int beg  = offsets[wave];
    const int end  = offsets[wave + 1];
    const int half = lane >> 5;
    const int hl   = lane & 31;
    float4 a0 = {0.f, 0.f, 0.f, 0.f};
    float4 a1 = {0.f, 0.f, 0.f, 0.f};
    int e = beg + half;
    for (; e + 2 < end; e += 4) {
        const int2 ed0 = sedge[e];
        const int2 ed1 = sedge[e + 2];
        const float m0 = __int_as_float(ed0.y);
        const float m1 = __int_as_float(ed1.y);
        const float4 v0 = *reinterpret_cast<const float4*>(x + (size_t)ed0.x * HIDDEN + hl * 4);
        const float4 v1 = *reinterpret_cast<const float4*>(x + (size_t)ed1.x * HIDDEN + hl * 4);
        a0.x += m0 * v0.x; a0.y += m0 * v0.y; a0.z += m0 * v0.z; a0.w += m0 * v0.w;
        a1.x += m1 * v1.x; a1.y += m1 * v1.y; a1.z += m1 * v1.z; a1.w += m1 * v1.w;
    }
    for (; e < end; e += 2) {
        const int2 ed = sedge[e];
        const float m = __int_as_float(ed.y);
        const float4 v = *reinterpret_cast<const float4*>(x + (size_t)ed.x * HIDDEN + hl * 4);
        a0.x += m * v.x; a0.y += m * v.y; a0.z += m * v.z; a0.w += m * v.w;
    }
    float4 a;
    a.x = a0.x + a1.x; a.y = a0.y + a1.y; a.z = a0.z + a1.z; a.w = a0.w + a1.w;
    a.x += __shfl(a.x, lane ^ 32, 64);
    a.y += __shfl(a.y, lane ^ 32, 64);
    a.z += __shfl(a.z, lane ^ 32, 64);
    a.w += __shfl(a.w, lane ^ 32, 64);
    if (half == 0) {
        *reinterpret_cast<float4*>(out + (size_t)wave * HIDDEN + hl * 4) = a;
    }
}

extern "C" void kernel_launch(void* const* d_in, const int* in_sizes, int n_in,
                              void* d_out, int out_size, void* d_ws, size_t ws_size,
                              hipStream_t stream) {
    const float* x        = (const float*)d_in[0];
    const float* w1       = (const float*)d_in[1];
    const float* w2       = (const float*)d_in[2];
    const float* adj_vals = (const float*)d_in[3];
    const int*   in_idx   = (const int*)d_in[4];
    const int*   out_idx  = (const int*)d_in[5];
    float* out = (float*)d_out;

    // workspace layout
    ushort* xh      = (ushort*)d_ws;                              // 25.6 MB
    int2*   sedge   = (int2*)(xh + (size_t)N_NODES * HIDDEN);     // 12.8 MB
    int2*   stage   = sedge + N_EDGES;                            // 12.8 MB
    float*  g1      = (float*)(stage + N_EDGES);                  // 0.4 MB
    float*  g2      = g1 + N_NODES;                               // 0.4 MB
    int*    offsets = (int*)(g2 + N_NODES);                       // 0.4 MB
    int*    cursor  = offsets + N_NODES + 1;                      // 0.4 MB (fallback)
    int*    tsum    = cursor + N_NODES;                           // 25.6 KB (fallback)
    int*    bcnt    = tsum + SCAN_THREADS;                        // NB
    int*    sbase   = bcnt + NB;                                  // NB+1
    int*    bcur    = sbase + NB + 1;                             // NB

    const size_t need_full = (size_t)((char*)(bcur + NB) - (char*)d_ws);
    const size_t need_old  = need_full - (size_t)N_EDGES * 8;     // without stage
    const int full_path = (ws_size >= need_full);
    const int bf16_ok   = (ws_size >= need_old);

    if (full_path) {
        // zero bucket counters
        fagcn_zero<<<1, 256, 0, stream>>>(bcnt);
        // fused gates + bucket histogram
        fagcn_gates_hist<<<GATES_B + HIST_B, 256, 0, stream>>>(
            x, w1, w2, in_idx, g1, g2, bcnt, xh, 1, 1);
        // bucket exclusive scan (also zeroes bcur)
        fagcn_scanb<<<1, 256, 0, stream>>>(bcnt, sbase, bcur);
        // partition: gate-free, minimal random ops per edge
        fagcn_part<<<PART_B, PART_T, 0, stream>>>(
            adj_vals, in_idx, out_idx, sbase, bcur, stage);
        // fine binning with lane-packed gate computation
        fagcn_fine<<<NB, NPB, 0, stream>>>(
            stage, sbase, g1, g2, offsets, sedge);
        // gather (pure, m precomputed), in two halves
        const int half_nodes = N_NODES / 2;                       // 50000
        fagcn_gather_bf16<<<(half_nodes + 3) / 4, 256, 0, stream>>>(
            xh, offsets, sedge, out, 0, half_nodes);
        fagcn_gather_bf16<<<(N_NODES - half_nodes + 3) / 4, 256, 0, stream>>>(
            xh, offsets, sedge, out, half_nodes, N_NODES);
    } else {
        // legacy path
        if (!bf16_ok) sedge = (int2*)d_ws;
        fagcn_gates_hist<<<GATES_B, 256, 0, stream>>>(
            x, w1, w2, in_idx, g1, g2, bcnt, xh, bf16_ok, 0);
        fagcn_zero_nodes<<<(N_NODES + 255) / 256, 256, 0, stream>>>(cursor);
        fagcn_hist<<<(N_EDGES + 255) / 256, 256, 0, stream>>>(in_idx, cursor);
        fagcn_scan1<<<SCAN_B, 256, 0, stream>>>(cursor, tsum);
        fagcn_scan2<<<1, 1024, 0, stream>>>(tsum);
        fagcn_scan3<<<SCAN_B, 256, 0, stream>>>(cursor, tsum, offsets);
        fagcn_bin<<<(N_EDGES + 255) / 256, 256, 0, stream>>>(
            adj_vals, in_idx, out_idx, g1, g2, offsets, cursor, sedge);
        if (bf16_ok) {
            fagcn_gather_bf16<<<(N_NODES + 3) / 4, 256, 0, stream>>>(
                xh, offsets, sedge, out, 0, N_NODES);
        } else {
            fagcn_gather_f32<<<(N_NODES + 3) / 4, 256, 0, stream>>>(
                x, offsets, sedge, out);
        }
    }
}

// Round 16
// 143.973 us; speedup vs baseline: 1.1977x; 1.0412x over previous
//
#include <hip/hip_runtime.h>

#define N_NODES 100000
#define N_EDGES 1600000
#define HIDDEN  128

// bucket partition geometry
#define NPB_SHIFT 9
#define NPB       512                                   // nodes per bucket
#define NB        ((N_NODES + NPB - 1) / NPB)           // 196 buckets
#define PART_T    1024                                  // threads per part block
#define PART_EPT  8                                     // edges per thread
#define PART_EPB  (PART_T * PART_EPT)                   // 8192 edges per block
#define PART_B    ((N_EDGES + PART_EPB - 1) / PART_EPB) // 196 blocks
#define HIST_EPT  16
#define HIST_EPB  (256 * HIST_EPT)                      // 4096
#define HIST_B    ((N_EDGES + HIST_EPB - 1) / HIST_EPB) // 391
#define GATES_B   ((N_NODES * 32 + 255) / 256)          // 12500 blocks
#define FINE_PE   20                                    // regs/thread in fine

// legacy-scan geometry (fallback path only)
#define SCAN_C 16
#define SCAN_T ((N_NODES + SCAN_C - 1) / SCAN_C)
#define SCAN_THREADS 6400
#define SCAN_B (SCAN_THREADS / 256)

// float -> bf16 round-to-nearest-even
__device__ __forceinline__ ushort f2bf(float f) {
    unsigned int u = __float_as_uint(f);
    u = (u + 0x7FFFu + ((u >> 16) & 1u)) >> 16;
    return (ushort)u;
}

// ---------------------------------------------------------------------------
// Tiny zero kernel: bcnt[NB] = 0
// ---------------------------------------------------------------------------
__global__ void fagcn_zero(int* __restrict__ bcnt) {
    const int t = (int)threadIdx.x;
    if (t < NB) bcnt[t] = 0;
}

// ---------------------------------------------------------------------------
// Fused kernel: blocks [0, GATES_B) do per-node gates (+bf16 x copy);
// blocks [GATES_B, GATES_B+HIST_B) do the bucket histogram of in_idx.
// ---------------------------------------------------------------------------
__global__ void fagcn_gates_hist(const float* __restrict__ x,
                                 const float* __restrict__ w1,
                                 const float* __restrict__ w2,
                                 const int*   __restrict__ in_idx,
                                 float* __restrict__ g1,
                                 float* __restrict__ g2,
                                 int*   __restrict__ bcnt,
                                 ushort* __restrict__ xh,
                                 int write_xh,
                                 int with_hist) {
    __shared__ int cnt[NB];
    if ((int)blockIdx.x < GATES_B) {
        // ---- gates role ----
        const int tid  = blockIdx.x * 256 + (int)threadIdx.x;
        const int node = tid >> 5;                 // 32 lanes per node
        const int hl   = (int)(threadIdx.x & 31);
        if (node >= N_NODES) return;

        const float4 xv  = *reinterpret_cast<const float4*>(x  + (size_t)node * HIDDEN + hl * 4);
        const float4 w1v = *reinterpret_cast<const float4*>(w1 + hl * 4);
        const float4 w2v = *reinterpret_cast<const float4*>(w2 + hl * 4);

        if (write_xh) {
            ushort4 h;
            h.x = f2bf(xv.x); h.y = f2bf(xv.y); h.z = f2bf(xv.z); h.w = f2bf(xv.w);
            *reinterpret_cast<ushort4*>(xh + (size_t)node * HIDDEN + hl * 4) = h;
        }

        float s1 = xv.x * w1v.x + xv.y * w1v.y + xv.z * w1v.z + xv.w * w1v.w;
        float s2 = xv.x * w2v.x + xv.y * w2v.y + xv.z * w2v.z + xv.w * w2v.w;

        #pragma unroll
        for (int off = 16; off > 0; off >>= 1) {
            s1 += __shfl_down(s1, off, 32);
            s2 += __shfl_down(s2, off, 32);
        }
        if (hl == 0) { g1[node] = s1; g2[node] = s2; }
    } else if (with_hist) {
        // ---- bucket histogram role ----
        const int tid  = (int)threadIdx.x;
        const int base = ((int)blockIdx.x - GATES_B) * HIST_EPB + tid * HIST_EPT;
        for (int j = tid; j < NB; j += 256) cnt[j] = 0;
        __syncthreads();
        if (base < N_EDGES) {                      // N_EDGES % HIST_EPT == 0
            #pragma unroll
            for (int i = 0; i < 4; ++i) {
                const int4 v = *reinterpret_cast<const int4*>(in_idx + base + i * 4);
                atomicAdd(&cnt[v.x >> NPB_SHIFT], 1);
                atomicAdd(&cnt[v.y >> NPB_SHIFT], 1);
                atomicAdd(&cnt[v.z >> NPB_SHIFT], 1);
                atomicAdd(&cnt[v.w >> NPB_SHIFT], 1);
            }
        }
        __syncthreads();
        for (int j = tid; j < NB; j += 256)
            if (cnt[j]) atomicAdd(&bcnt[j], cnt[j]);
    }
}

// ---------------------------------------------------------------------------
// Bucket scan: exclusive scan of NB bucket counts -> sbase (1 tiny block);
// sbase[NB] = N_EDGES; zeroes bcur.
// ---------------------------------------------------------------------------
__global__ void fagcn_scanb(const int* __restrict__ bcnt,
                            int* __restrict__ sbase,
                            int* __restrict__ bcur) {
    __shared__ int l[256];
    const int t = (int)threadIdx.x;
    const int c = (t < NB) ? bcnt[t] : 0;
    l[t] = c;
    __syncthreads();
    for (int off = 1; off < 256; off <<= 1) {
        int v = (t >= off) ? l[t - off] : 0;
        __syncthreads();
        l[t] += v;
        __syncthreads();
    }
    if (t < NB) { sbase[t] = l[t] - c; bcur[t] = 0; }
    if (t == NB - 1) sbase[NB] = l[t];             // == N_EDGES
}

// ---------------------------------------------------------------------------
// Partition pass: 196 blocks x 1024 threads x EPT 8 (16 waves/CU, same 38K
// chunk boundaries). Rank-from-count: first-phase atomic return value is the
// intra-block rank -> scatter phase has NO LDS atomics.
// ---------------------------------------------------------------------------
__global__ void fagcn_part(const float* __restrict__ adj,
                           const int*   __restrict__ in_idx,
                           const int*   __restrict__ out_idx,
                           const int*   __restrict__ sbase,
                           int*         __restrict__ bcur,
                           int2*        __restrict__ stage) {
    __shared__ int cnt[NB], lbase[NB];
    const int tid  = (int)threadIdx.x;                 // 0..1023
    const int base = blockIdx.x * PART_EPB + tid * PART_EPT;

    for (int j = tid; j < NB; j += PART_T) cnt[j] = 0;
    __syncthreads();

    int s[PART_EPT], rank[PART_EPT];
    const bool act = (base < N_EDGES);                 // N_EDGES % PART_EPT == 0
    if (act) {
        #pragma unroll
        for (int i = 0; i < PART_EPT / 4; ++i) {
            const int4 v = *reinterpret_cast<const int4*>(in_idx + base + i * 4);
            s[4 * i + 0] = v.x; s[4 * i + 1] = v.y;
            s[4 * i + 2] = v.z; s[4 * i + 3] = v.w;
        }
        #pragma unroll
        for (int i = 0; i < PART_EPT; ++i)
            rank[i] = atomicAdd(&cnt[s[i] >> NPB_SHIFT], 1);
    }
    __syncthreads();
    for (int j = tid; j < NB; j += PART_T)
        if (cnt[j] > 0) lbase[j] = sbase[j] + atomicAdd(&bcur[j], cnt[j]);
    __syncthreads();
    if (act) {
        #pragma unroll
        for (int i = 0; i < PART_EPT / 4; ++i) {
            const int4   d4 = *reinterpret_cast<const int4*>(out_idx + base + i * 4);
            const float4 a4 = *reinterpret_cast<const float4*>(adj + base + i * 4);
            const int   dd[4] = {d4.x, d4.y, d4.z, d4.w};
            const float aa[4] = {a4.x, a4.y, a4.z, a4.w};
            #pragma unroll
            for (int k = 0; k < 4; ++k) {
                const int e   = 4 * i + k;
                const int src = s[e];
                const int b   = src >> NPB_SHIFT;
                stage[lbase[b] + rank[e]] =
                    make_int2(((src & (NPB - 1)) << 17) | dd[k],
                              __float_as_int(aa[k]));
            }
        }
    }
}

// ---------------------------------------------------------------------------
// Fine binning WITH gate. Rank-from-count (no scatter atomics) +
// wave-shuffle scan (2 barriers instead of 18).
// ---------------------------------------------------------------------------
__global__ void fagcn_fine(const int2* __restrict__ stage,
                           const int*  __restrict__ sbase,
                           const float* __restrict__ g1,
                           const float* __restrict__ g2,
                           int*        __restrict__ offsets,
                           int2*       __restrict__ sedge) {
    __shared__ int   cnt[NPB];
    __shared__ int   nbase[NPB];
    __shared__ int   wsum[NPB / 64];
    __shared__ float g1s[NPB];
    const int b    = (int)blockIdx.x;
    const int t    = (int)threadIdx.x;         // 0..511
    const int w    = t >> 6;
    const int lane = t & 63;

    const int ebeg = sbase[b];
    const int eend = sbase[b + 1];
    const int node = (b << NPB_SHIFT) + t;

    g1s[t] = (node < N_NODES) ? g1[node] : 0.f;
    cnt[t] = 0;
    __syncthreads();

    // load payload, issue g2 gathers (MLP), count + grab rank in one atomic
    int2  pay[FINE_PE];
    float gv[FINE_PE];
    int   rank[FINE_PE];
    #pragma unroll
    for (int i = 0; i < FINE_PE; ++i) {
        const int e = ebeg + t + i * NPB;
        if (e < eend) {
            pay[i]  = stage[e];
            gv[i]   = g2[pay[i].x & 0x1FFFF];
            rank[i] = atomicAdd(&cnt[(unsigned)pay[i].x >> 17], 1);
        }
    }
    __syncthreads();

    // exclusive scan over NPB node counts: wave-shuffle inclusive scan,
    // then tiny serial scan of the 8 wave totals.
    const int c = cnt[t];
    int v = c;
    #pragma unroll
    for (int off = 1; off < 64; off <<= 1) {
        const int u = __shfl_up(v, off, 64);
        if (lane >= off) v += u;
    }
    if (lane == 63) wsum[w] = v;
    __syncthreads();
    if (t == 0) {
        int acc = 0;
        #pragma unroll
        for (int j = 0; j < NPB / 64; ++j) {
            const int xw = wsum[j];
            wsum[j] = acc;
            acc += xw;
        }
    }
    __syncthreads();
    const int excl = v - c + wsum[w];
    nbase[t] = ebeg + excl;
    if (node < N_NODES) offsets[node] = ebeg + excl;
    if (b == (int)gridDim.x - 1 && t == 0) offsets[N_NODES] = N_EDGES;
    __syncthreads();

    // lane-packed gate + atomic-free scatter into block-exclusive CSR region
    #pragma unroll
    for (int i = 0; i < FINE_PE; ++i) {
        const int e = ebeg + t + i * NPB;
        if (e < eend) {
            const int slocal = (unsigned)pay[i].x >> 17;
            const float m = tanhf(g1s[slocal] + gv[i]) * __int_as_float(pay[i].y);
            sedge[nbase[slocal] + rank[i]] =
                make_int2(pay[i].x & 0x1FFFF, __float_as_int(m));
        }
    }
}

// ---------------------------------------------------------------------------
// fma 8 bf16 elements (packed in a uint4) into a[0..7]
// ---------------------------------------------------------------------------
__device__ __forceinline__ void acc8(float* a, uint4 v, float m) {
    const unsigned int u[4] = {v.x, v.y, v.z, v.w};
    #pragma unroll
    for (int i = 0; i < 4; ++i) {
        const float lo = __uint_as_float(u[i] << 16);
        const float hi = __uint_as_float(u[i] & 0xFFFF0000u);
        a[2 * i]     += m * lo;
        a[2 * i + 1] += m * hi;
    }
}

// ---------------------------------------------------------------------------
// Gather-accumulate (bf16): m precomputed in sedge. One wave per node,
// 4 slot-phases of 16 lanes. Single dispatch over all nodes.
// ---------------------------------------------------------------------------
__global__ void fagcn_gather_bf16(const ushort* __restrict__ xh,
                                  const int*   __restrict__ offsets,
                                  const int2*  __restrict__ sedge,
                                  float*       __restrict__ out) {
    const int wave = (int)((blockIdx.x * blockDim.x + threadIdx.x) >> 6);
    const int lane = (int)(threadIdx.x & 63);
    if (wave >= N_NODES) return;

    const int beg = offsets[wave];
    const int end = offsets[wave + 1];
    const int q   = lane >> 4;
    const int ql  = lane & 15;

    float a[8] = {0.f, 0.f, 0.f, 0.f, 0.f, 0.f, 0.f, 0.f};
    float b[8] = {0.f, 0.f, 0.f, 0.f, 0.f, 0.f, 0.f, 0.f};

    int e = beg + q;
    for (; e + 12 < end; e += 16) {
        const int2 ed0 = sedge[e];
        const int2 ed1 = sedge[e + 4];
        const int2 ed2 = sedge[e + 8];
        const int2 ed3 = sedge[e + 12];
        const uint4 v0 = *reinterpret_cast<const uint4*>(xh + (size_t)ed0.x * HIDDEN + ql * 8);
        const uint4 v1 = *reinterpret_cast<const uint4*>(xh + (size_t)ed1.x * HIDDEN + ql * 8);
        const uint4 v2 = *reinterpret_cast<const uint4*>(xh + (size_t)ed2.x * HIDDEN + ql * 8);
        const uint4 v3 = *reinterpret_cast<const uint4*>(xh + (size_t)ed3.x * HIDDEN + ql * 8);
        acc8(a, v0, __int_as_float(ed0.y));
        acc8(b, v1, __int_as_float(ed1.y));
        acc8(a, v2, __int_as_float(ed2.y));
        acc8(b, v3, __int_as_float(ed3.y));
    }
    for (; e < end; e += 4) {
        const int2 ed = sedge[e];
        const uint4 v = *reinterpret_cast<const uint4*>(xh + (size_t)ed.x * HIDDEN + ql * 8);
        acc8(a, v, __int_as_float(ed.y));
    }

    float r[8];
    #pragma unroll
    for (int i = 0; i < 8; ++i) r[i] = a[i] + b[i];
    #pragma unroll
    for (int i = 0; i < 8; ++i) r[i] += __shfl(r[i], lane ^ 16, 64);
    #pragma unroll
    for (int i = 0; i < 8; ++i) r[i] += __shfl(r[i], lane ^ 32, 64);

    if (lane < 16) {
        float* o = out + (size_t)wave * HIDDEN + ql * 8;
        float4 lo = {r[0], r[1], r[2], r[3]};
        float4 hi = {r[4], r[5], r[6], r[7]};
        *reinterpret_cast<float4*>(o)     = lo;
        *reinterpret_cast<float4*>(o + 4) = hi;
    }
}

// ===========================================================================
// Fallback path (round-6 structure, m computed in bin) — small-ws only.
// ===========================================================================
__global__ void fagcn_hist(const int* __restrict__ in_idx,
                           int* __restrict__ counts) {
    const int e = blockIdx.x * blockDim.x + threadIdx.x;
    if (e < N_EDGES) atomicAdd(&counts[in_idx[e]], 1);
}

__global__ void fagcn_zero_nodes(int* __restrict__ counts) {
    const int i = blockIdx.x * blockDim.x + threadIdx.x;
    if (i < N_NODES) counts[i] = 0;
}

__global__ void fagcn_scan1(const int* __restrict__ counts,
                            int* __restrict__ tsum) {
    const int t = blockIdx.x * blockDim.x + threadIdx.x;
    if (t >= SCAN_THREADS) return;
    int s = 0;
    if (t < SCAN_T) {
        const int beg = t * SCAN_C;
        const int end = (beg + SCAN_C < N_NODES) ? beg + SCAN_C : N_NODES;
        for (int i = beg; i < end; ++i) s += counts[i];
    }
    tsum[t] = s;
}

__global__ void fagcn_scan2(int* __restrict__ tsum) {
    __shared__ int lsum[1024];
    const int t = (int)threadIdx.x;
    const int C = (SCAN_THREADS + 1023) / 1024;
    const int beg = t * C;
    const int end = (beg + C < SCAN_THREADS) ? beg + C : SCAN_THREADS;
    int s = 0;
    for (int i = beg; i < end; ++i) s += tsum[i];
    lsum[t] = s;
    __syncthreads();
    for (int off = 1; off < 1024; off <<= 1) {
        int v = (t >= off) ? lsum[t - off] : 0;
        __syncthreads();
        lsum[t] += v;
        __syncthreads();
    }
    int prefix = (t == 0) ? 0 : lsum[t - 1];
    for (int i = beg; i < end; ++i) {
        const int v = tsum[i];
        tsum[i] = prefix;
        prefix += v;
    }
}

__global__ void fagcn_scan3(int* counts,
                            const int* __restrict__ tsum,
                            int* __restrict__ offsets) {
    const int t = blockIdx.x * blockDim.x + threadIdx.x;
    if (t >= SCAN_T) return;
    const int beg = t * SCAN_C;
    const int end = (beg + SCAN_C < N_NODES) ? beg + SCAN_C : N_NODES;
    int prefix = tsum[t];
    for (int i = beg; i < end; ++i) {
        const int c = counts[i];
        offsets[i] = prefix;
        prefix += c;
        counts[i] = 0;
    }
    if (t == 0) offsets[N_NODES] = N_EDGES;
}

__global__ void fagcn_bin(const float* __restrict__ adj,
                          const int*   __restrict__ in_idx,
                          const int*   __restrict__ out_idx,
                          const float* __restrict__ g1,
                          const float* __restrict__ g2,
                          const int*   __restrict__ offsets,
                          int*         __restrict__ cursor,
                          int2*        __restrict__ sedge) {
    const int e = blockIdx.x * blockDim.x + threadIdx.x;
    if (e >= N_EDGES) return;
    const int src = in_idx[e];
    const int dst = out_idx[e];
    const float m = tanhf(g1[src] + g2[dst]) * adj[e];
    const int pos = offsets[src] + atomicAdd(&cursor[src], 1);
    sedge[pos] = make_int2(dst, __float_as_int(m));
}

__global__ void fagcn_gather_f32(const float* __restrict__ x,
                                 const int*   __restrict__ offsets,
                                 const int2*  __restrict__ sedge,
                                 float*       __restrict__ out) {
    const int wave = (int)((blockIdx.x * blockDim.x + threadIdx.x) >> 6);
    const int lane = (int)(threadIdx.x & 63);
    if (wave >= N_NODES) return;
    const int beg  = offsets[wave];
    const int end  = offsets[wave + 1];
    const int half = lane >> 5;
    const int hl   = lane & 31;
    float4 a0 = {0.f, 0.f, 0.f, 0.f};
    float4 a1 = {0.f, 0.f, 0.f, 0.f};
    int e = beg + half;
    for (; e + 2 < end; e += 4) {
        const int2 ed0 = sedge[e];
        const int2 ed1 = sedge[e + 2];
        const float m0 = __int_as_float(ed0.y);
        const float m1 = __int_as_float(ed1.y);
        const float4 v0 = *reinterpret_cast<const float4*>(x + (size_t)ed0.x * HIDDEN + hl * 4);
        const float4 v1 = *reinterpret_cast<const float4*>(x + (size_t)ed1.x * HIDDEN + hl * 4);
        a0.x += m0 * v0.x; a0.y += m0 * v0.y; a0.z += m0 * v0.z; a0.w += m0 * v0.w;
        a1.x += m1 * v1.x; a1.y += m1 * v1.y; a1.z += m1 * v1.z; a1.w += m1 * v1.w;
    }
    for (; e < end; e += 2) {
        const int2 ed = sedge[e];
        const float m = __int_as_float(ed.y);
        const float4 v = *reinterpret_cast<const float4*>(x + (size_t)ed.x * HIDDEN + hl * 4);
        a0.x += m * v.x; a0.y += m * v.y; a0.z += m * v.z; a0.w += m * v.w;
    }
    float4 a;
    a.x = a0.x + a1.x; a.y = a0.y + a1.y; a.z = a0.z + a1.z; a.w = a0.w + a1.w;
    a.x += __shfl(a.x, lane ^ 32, 64);
    a.y += __shfl(a.y, lane ^ 32, 64);
    a.z += __shfl(a.z, lane ^ 32, 64);
    a.w += __shfl(a.w, lane ^ 32, 64);
    if (half == 0) {
        *reinterpret_cast<float4*>(out + (size_t)wave * HIDDEN + hl * 4) = a;
    }
}

extern "C" void kernel_launch(void* const* d_in, const int* in_sizes, int n_in,
                              void* d_out, int out_size, void* d_ws, size_t ws_size,
                              hipStream_t stream) {
    const float* x        = (const float*)d_in[0];
    const float* w1       = (const float*)d_in[1];
    const float* w2       = (const float*)d_in[2];
    const float* adj_vals = (const float*)d_in[3];
    const int*   in_idx   = (const int*)d_in[4];
    const int*   out_idx  = (const int*)d_in[5];
    float* out = (float*)d_out;

    // workspace layout
    ushort* xh      = (ushort*)d_ws;                              // 25.6 MB
    int2*   sedge   = (int2*)(xh + (size_t)N_NODES * HIDDEN);     // 12.8 MB
    int2*   stage   = sedge + N_EDGES;                            // 12.8 MB
    float*  g1      = (float*)(stage + N_EDGES);                  // 0.4 MB
    float*  g2      = g1 + N_NODES;                               // 0.4 MB
    int*    offsets = (int*)(g2 + N_NODES);                       // 0.4 MB
    int*    cursor  = offsets + N_NODES + 1;                      // 0.4 MB (fallback)
    int*    tsum    = cursor + N_NODES;                           // 25.6 KB (fallback)
    int*    bcnt    = tsum + SCAN_THREADS;                        // NB
    int*    sbase   = bcnt + NB;                                  // NB+1
    int*    bcur    = sbase + NB + 1;                             // NB

    const size_t need_full = (size_t)((char*)(bcur + NB) - (char*)d_ws);
    const size_t need_old  = need_full - (size_t)N_EDGES * 8;     // without stage
    const int full_path = (ws_size >= need_full);
    const int bf16_ok   = (ws_size >= need_old);

    if (full_path) {
        // zero bucket counters
        fagcn_zero<<<1, 256, 0, stream>>>(bcnt);
        // fused gates + bucket histogram
        fagcn_gates_hist<<<GATES_B + HIST_B, 256, 0, stream>>>(
            x, w1, w2, in_idx, g1, g2, bcnt, xh, 1, 1);
        // bucket exclusive scan (also zeroes bcur)
        fagcn_scanb<<<1, 256, 0, stream>>>(bcnt, sbase, bcur);
        // partition: 1024-thread blocks, rank-from-count scatter
        fagcn_part<<<PART_B, PART_T, 0, stream>>>(
            adj_vals, in_idx, out_idx, sbase, bcur, stage);
        // fine binning: gate + wave-shuffle scan + atomic-free scatter
        fagcn_fine<<<NB, NPB, 0, stream>>>(
            stage, sbase, g1, g2, offsets, sedge);
        // gather (single dispatch)
        fagcn_gather_bf16<<<(N_NODES + 3) / 4, 256, 0, stream>>>(
            xh, offsets, sedge, out);
    } else {
        // legacy path
        if (!bf16_ok) sedge = (int2*)d_ws;
        fagcn_gates_hist<<<GATES_B, 256, 0, stream>>>(
            x, w1, w2, in_idx, g1, g2, bcnt, xh, bf16_ok, 0);
        fagcn_zero_nodes<<<(N_NODES + 255) / 256, 256, 0, stream>>>(cursor);
        fagcn_hist<<<(N_EDGES + 255) / 256, 256, 0, stream>>>(in_idx, cursor);
        fagcn_scan1<<<SCAN_B, 256, 0, stream>>>(cursor, tsum);
        fagcn_scan2<<<1, 1024, 0, stream>>>(tsum);
        fagcn_scan3<<<SCAN_B, 256, 0, stream>>>(cursor, tsum, offsets);
        fagcn_bin<<<(N_EDGES + 255) / 256, 256, 0, stream>>>(
            adj_vals, in_idx, out_idx, g1, g2, offsets, cursor, sedge);
        if (bf16_ok) {
            fagcn_gather_bf16<<<(N_NODES + 3) / 4, 256, 0, stream>>>(
                xh, offsets, sedge, out);
        } else {
            fagcn_gather_f32<<<(N_NODES + 3) / 4, 256, 0, stream>>>(
                x, offsets, sedge, out);
        }
    }
}